// Round 6
// baseline (198.034 us; speedup 1.0000x reference)
//
#include <hip/hip_runtime.h>
#include <hip/hip_bf16.h>

// Problem constants: B=4,S=2048 -> T=8192 tokens, H=1024, E=8, TOP_K=2
#define H 1024
#define NEXP 8
#define T_TOK 8192
#define CAP 8192
#define TM 128
#define TN 128
#define TPB 16
#define CNTSTRIDE 32

typedef __bf16 bf16x8 __attribute__((ext_vector_type(8)));
typedef __bf16 bf16x4 __attribute__((ext_vector_type(4)));
typedef float f32x4 __attribute__((ext_vector_type(4)));

__device__ __forceinline__ void async16(void* lds, const void* g) {
    __builtin_amdgcn_global_load_lds(
        (const __attribute__((address_space(1))) void*)g,
        (__attribute__((address_space(3))) void*)lds, 16, 0, 0);
}

// ---------------- routing: fp32 logits, top-2, gates; fused x -> bf16 cast ----------------
__global__ __launch_bounds__(256) void moe_route(
    const float* __restrict__ x, const float* __restrict__ Wg,
    __bf16* __restrict__ Xb, int* __restrict__ cnt,
    int* __restrict__ ltok, float* __restrict__ lgate,
    int* __restrict__ tsel, float* __restrict__ tgate) {
    const int tid  = threadIdx.x;
    const int lane = tid & 63;
    const int wave = tid >> 6;
    const int base = blockIdx.x * TPB;

    __shared__ int   sE[TPB * 2];
    __shared__ float sG[TPB * 2];
    __shared__ int   lcnt[NEXP], lbase[NEXP], lslot[TPB * 2];

    for (int i = 0; i < TPB / 4; ++i) {          // 4 tokens per wave
        const int tl = wave * (TPB / 4) + i;
        const int t  = base + tl;
        const float* xr  = x  + (size_t)t * H;
        __bf16*      xbr = Xb + (size_t)t * H;
        float a[NEXP];
#pragma unroll
        for (int e = 0; e < NEXP; ++e) a[e] = 0.f;
#pragma unroll
        for (int j = 0; j < H / 256; ++j) {
            const int h = j * 256 + lane * 4;
            const float4 xv = *(const float4*)(xr + h);
            bf16x4 xo;
            xo[0] = (__bf16)xv.x; xo[1] = (__bf16)xv.y;
            xo[2] = (__bf16)xv.z; xo[3] = (__bf16)xv.w;
            *(bf16x4*)(xbr + h) = xo;
            const float xc[4] = {xv.x, xv.y, xv.z, xv.w};
#pragma unroll
            for (int c = 0; c < 4; ++c) {
                const float4 w0 = *(const float4*)(Wg + (h + c) * NEXP);
                const float4 w1 = *(const float4*)(Wg + (h + c) * NEXP + 4);
                a[0] += xc[c] * w0.x; a[1] += xc[c] * w0.y; a[2] += xc[c] * w0.z; a[3] += xc[c] * w0.w;
                a[4] += xc[c] * w1.x; a[5] += xc[c] * w1.y; a[6] += xc[c] * w1.z; a[7] += xc[c] * w1.w;
            }
        }
#pragma unroll
        for (int e = 0; e < NEXP; ++e) {
#pragma unroll
            for (int off = 32; off > 0; off >>= 1)
                a[e] += __shfl_xor(a[e], off, 64);
        }
        int i0 = 0;
#pragma unroll
        for (int e = 1; e < NEXP; ++e) if (a[e] > a[i0]) i0 = e;   // jax tie-break: lowest idx
        int i1 = (i0 == 0) ? 1 : 0;
#pragma unroll
        for (int e = 0; e < NEXP; ++e) if (e != i0 && a[e] > a[i1]) i1 = e;
        const float ex = __expf(a[i1] - a[i0]);
        const float g0 = 1.f / (1.f + ex);
        const float g1 = ex / (1.f + ex);
        if (lane == 0) {
            sE[tl * 2] = i0; sE[tl * 2 + 1] = i1;
            sG[tl * 2] = g0; sG[tl * 2 + 1] = g1;
        }
    }
    if (tid < NEXP) lcnt[tid] = 0;
    __syncthreads();
    if (tid < TPB * 2) lslot[tid] = atomicAdd(&lcnt[sE[tid]], 1);
    __syncthreads();
    if (tid < NEXP) lbase[tid] = lcnt[tid] ? atomicAdd(&cnt[tid * CNTSTRIDE], lcnt[tid]) : 0;
    __syncthreads();
    if (tid < TPB * 2) {
        const int e = sE[tid];
        const int s = lbase[e] + lslot[tid];
        const int t = base + (tid >> 1);
        ltok[e * CAP + s]  = t;
        lgate[e * CAP + s] = sG[tid];
        tsel[t * 2 + (tid & 1)]  = e * CAP + s;
        tgate[t * 2 + (tid & 1)] = sG[tid];
    }
}

// ---------------- We (E,h,d) fp32 -> WeT (E,d,h) bf16 : 64x64 tiles, vectorized ----------------
__global__ __launch_bounds__(256) void cast_transpose_we(
    const float* __restrict__ We, __bf16* __restrict__ WeT) {
    __shared__ float t[64][65];
    const int e  = blockIdx.z;
    const int d0 = blockIdx.x * 64;
    const int h0 = blockIdx.y * 64;
    const int tx = threadIdx.x & 15;
    const int ty = threadIdx.x >> 4;
    const float* src = We + ((size_t)e << 20);
    __bf16* dst = WeT + ((size_t)e << 20);
#pragma unroll
    for (int p = 0; p < 4; ++p) {
        const int row = p * 16 + ty;
        const float4 v = *(const float4*)(src + (size_t)(h0 + row) * H + d0 + tx * 4);
        t[row][tx * 4 + 0] = v.x; t[row][tx * 4 + 1] = v.y;
        t[row][tx * 4 + 2] = v.z; t[row][tx * 4 + 3] = v.w;
    }
    __syncthreads();
#pragma unroll
    for (int p = 0; p < 4; ++p) {
        const int drow = p * 16 + ty;
        bf16x4 o;
        o[0] = (__bf16)t[tx * 4 + 0][drow];
        o[1] = (__bf16)t[tx * 4 + 1][drow];
        o[2] = (__bf16)t[tx * 4 + 2][drow];
        o[3] = (__bf16)t[tx * 4 + 3][drow];
        *(bf16x4*)(dst + (size_t)(d0 + drow) * H + h0 + tx * 4) = o;
    }
}

// ---------------- grouped GEMM: 128x128 tile, BK=64 (two BK=32 panels), bf16 MFMA ----------------
// R5 fix: epilogue stages C through LDS (reusing the 32KB panel buffers, per-wave 8KB)
// and stores bf16x8 full-128B-line bursts. R5 counters showed FETCH 113MB vs ideal 34MB:
// ~33MB was TCC read-for-ownership on the old 2B-scalar partial-line Eout writes.
__global__ __launch_bounds__(256) void moe_gemm(
    const __bf16* __restrict__ Xb, const __bf16* __restrict__ WeT,
    const float* __restrict__ be, const int* __restrict__ cnt,
    const int* __restrict__ ltok, const float* __restrict__ lgate,
    __bf16* __restrict__ Eout) {
    const int e = blockIdx.z;
    const int ne = cnt[e * CNTSTRIDE];
    const int m0 = blockIdx.y * TM;
    if (m0 >= ne) return;
    const int n0 = blockIdx.x * TN;
    int off = 0;
    for (int i2 = 0; i2 < e; ++i2) off += cnt[i2 * CNTSTRIDE];

    __shared__ __align__(16) __bf16 smem[4 * 4096];  // Al|Al2|Bl|Bl2; epilogue: 4 x (64x64)
    __bf16* Al  = smem;
    __bf16* Al2 = smem + 4096;
    __bf16* Bl  = smem + 8192;
    __bf16* Bl2 = smem + 12288;
    __shared__ int tokL[TM];

    const int tid = threadIdx.x;
    const int lane = tid & 63;
    const int wave = tid >> 6;

    if (tid < TM) {
        const int gi = m0 + tid;
        tokL[tid] = (gi < ne) ? ltok[e * CAP + gi] : 0;
    }
    __syncthreads();

    const __bf16* Bt = WeT + ((size_t)e << 20);
    const int qr = lane >> 4;
    const int rr = lane & 15;
    const int wr = (wave >> 1) * 64;
    const int wc = (wave & 1) * 64;

    f32x4 acc[4][4];
    const f32x4 z = {0.f, 0.f, 0.f, 0.f};
#pragma unroll
    for (int i = 0; i < 4; ++i)
#pragma unroll
        for (int j = 0; j < 4; ++j) acc[i][j] = z;

    const int c0 = tid, c1 = tid + 256;
    const int ar0 = c0 >> 2, ak0 = (((c0 & 3) ^ ((c0 >> 3) & 3)) * 8);
    const int ar1 = c1 >> 2, ak1 = (((c1 & 3) ^ ((c1 >> 3) & 3)) * 8);
    const size_t arow0 = (size_t)tokL[ar0] * H;
    const size_t arow1 = (size_t)tokL[ar1] * H;
    const size_t brow0 = (size_t)(n0 + ar0) * H;
    const size_t brow1 = (size_t)(n0 + ar1) * H;

    for (int k0 = 0; k0 < H; k0 += 64) {
        async16(&Al [c0 * 8], Xb + arow0 + k0 + ak0);
        async16(&Al [c1 * 8], Xb + arow1 + k0 + ak1);
        async16(&Al2[c0 * 8], Xb + arow0 + k0 + 32 + ak0);
        async16(&Al2[c1 * 8], Xb + arow1 + k0 + 32 + ak1);
        async16(&Bl [c0 * 8], Bt + brow0 + k0 + ak0);
        async16(&Bl [c1 * 8], Bt + brow1 + k0 + ak1);
        async16(&Bl2[c0 * 8], Bt + brow0 + k0 + 32 + ak0);
        async16(&Bl2[c1 * 8], Bt + brow1 + k0 + 32 + ak1);
        __syncthreads();
        {
            bf16x8 af[4], bfr[4];
#pragma unroll
            for (int i = 0; i < 4; ++i) {
                const int ra = wr + i * 16 + rr;
                af[i] = *(const bf16x8*)&Al[ra * 32 + ((qr ^ ((ra >> 1) & 3)) * 8)];
            }
#pragma unroll
            for (int j = 0; j < 4; ++j) {
                const int rb = wc + j * 16 + rr;
                bfr[j] = *(const bf16x8*)&Bl[rb * 32 + ((qr ^ ((rb >> 1) & 3)) * 8)];
            }
#pragma unroll
            for (int i = 0; i < 4; ++i)
#pragma unroll
                for (int j = 0; j < 4; ++j)
                    acc[i][j] = __builtin_amdgcn_mfma_f32_16x16x32_bf16(af[i], bfr[j], acc[i][j], 0, 0, 0);
        }
        {
            bf16x8 af[4], bfr[4];
#pragma unroll
            for (int i = 0; i < 4; ++i) {
                const int ra = wr + i * 16 + rr;
                af[i] = *(const bf16x8*)&Al2[ra * 32 + ((qr ^ ((ra >> 1) & 3)) * 8)];
            }
#pragma unroll
            for (int j = 0; j < 4; ++j) {
                const int rb = wc + j * 16 + rr;
                bfr[j] = *(const bf16x8*)&Bl2[rb * 32 + ((qr ^ ((rb >> 1) & 3)) * 8)];
            }
#pragma unroll
            for (int i = 0; i < 4; ++i)
#pragma unroll
                for (int j = 0; j < 4; ++j)
                    acc[i][j] = __builtin_amdgcn_mfma_f32_16x16x32_bf16(af[i], bfr[j], acc[i][j], 0, 0, 0);
        }
        __syncthreads();   // also protects smem reuse by the epilogue on the last iter
    }

    float bev[4];
#pragma unroll
    for (int j = 0; j < 4; ++j) bev[j] = be[e * H + n0 + wc + j * 16 + rr];

    // ---- epilogue: per-wave 64x64 LDS stage (XOR col swizzle), then full-line bf16x8 stores ----
    __bf16* Cw = smem + wave * 4096;
#pragma unroll
    for (int i = 0; i < 4; ++i) {
#pragma unroll
        for (int reg = 0; reg < 4; ++reg) {
            const int row = i * 16 + qr * 4 + reg;      // C/D layout: col=lane&15, row=quad*4+reg
            const int key = (row & 7) * 8;
#pragma unroll
            for (int j = 0; j < 4; ++j) {
                const int c = j * 16 + rr;
                Cw[row * 64 + (c ^ key)] = (__bf16)(acc[i][j][reg] + bev[j]);
            }
        }
    }
    // same-wave LDS dependency: compiler inserts lgkmcnt wait
    const int lrr = lane & 7, lrg = lane >> 3;
#pragma unroll
    for (int p = 0; p < 8; ++p) {
        const int row = p * 8 + lrg;
        const int rglob = m0 + wr + row;
        if (rglob < ne) {
            const int idx8 = ((lrr ^ (row & 7)) * 8);
            const bf16x8 v = *(const bf16x8*)&Cw[row * 64 + idx8];
            *(bf16x8*)(Eout + (size_t)(off + rglob) * H + n0 + wc + lrr * 8) = v;
        }
    }
}

// ---------------- combine: wave per token, out[t] = g0*row0 + g1*row1 ----------------
__global__ __launch_bounds__(256) void moe_combine(
    const __bf16* __restrict__ Eout, const int* __restrict__ cnt,
    const int* __restrict__ tsel, const float* __restrict__ tgate,
    float* __restrict__ out) {
    __shared__ int offs[NEXP];
    if (threadIdx.x < NEXP) {
        int o = 0;
        for (int i = 0; i < (int)threadIdx.x; ++i) o += cnt[i * CNTSTRIDE];
        offs[threadIdx.x] = o;
    }
    __syncthreads();
    const int wave = threadIdx.x >> 6, lane = threadIdx.x & 63;
    const int t = blockIdx.x * 4 + wave;
    const int sel0 = tsel[t * 2],  sel1 = tsel[t * 2 + 1];
    const float g0 = tgate[t * 2], g1  = tgate[t * 2 + 1];
    const int e0 = sel0 >> 13, s0 = sel0 & (CAP - 1);
    const int e1 = sel1 >> 13, s1 = sel1 & (CAP - 1);
    const __bf16* r0 = Eout + (size_t)(offs[e0] + s0) * H;
    const __bf16* r1 = Eout + (size_t)(offs[e1] + s1) * H;
    float* orow = out + (size_t)t * H;
#pragma unroll
    for (int c = 0; c < 4; ++c) {
        const int d = c * 256 + lane * 4;
        const bf16x4 a = *(const bf16x4*)(r0 + d);
        const bf16x4 b = *(const bf16x4*)(r1 + d);
        float4 o;
        o.x = g0 * (float)a[0] + g1 * (float)b[0];
        o.y = g0 * (float)a[1] + g1 * (float)b[1];
        o.z = g0 * (float)a[2] + g1 * (float)b[2];
        o.w = g0 * (float)a[3] + g1 * (float)b[3];
        *(float4*)(orow + d) = o;
    }
}

extern "C" void kernel_launch(void* const* d_in, const int* in_sizes, int n_in,
                              void* d_out, int out_size, void* d_ws, size_t ws_size,
                              hipStream_t stream) {
    const float* x  = (const float*)d_in[0];
    const float* Wg = (const float*)d_in[1];
    const float* We = (const float*)d_in[2];
    const float* be = (const float*)d_in[3];
    float* out = (float*)d_out;

    char* ws = (char*)d_ws;
    __bf16* Xb   = (__bf16*)ws;
    __bf16* WeT  = (__bf16*)(ws + ((size_t)16 << 20));
    __bf16* Eout = (__bf16*)(ws + ((size_t)32 << 20));
    char*   meta = ws + ((size_t)64 << 20);
    int*    cnt  = (int*)meta;
    int*    ltok = (int*)(meta + 1024);
    float*  lgat = (float*)(meta + 1024 + (size_t)NEXP * CAP * 4);
    int*    tsel = (int*)(meta + 1024 + (size_t)NEXP * CAP * 8);
    float*  tgat = (float*)(meta + 1024 + (size_t)NEXP * CAP * 8 + (size_t)T_TOK * 8);

    hipMemsetAsync(cnt, 0, NEXP * CNTSTRIDE * sizeof(int), stream);

    cast_transpose_we<<<dim3(H / 64, H / 64, NEXP), 256, 0, stream>>>(We, WeT);
    moe_route<<<T_TOK / TPB, 256, 0, stream>>>(x, Wg, Xb, cnt, ltok, lgat, tsel, tgat);
    moe_gemm<<<dim3(H / TN, T_TOK / TM, NEXP), 256, 0, stream>>>(Xb, WeT, be, cnt, ltok, lgat, Eout);
    moe_combine<<<T_TOK / 4, 256, 0, stream>>>(Eout, cnt, tsel, tgat, out);
}

// Round 7
// 191.240 us; speedup vs baseline: 1.0355x; 1.0355x over previous
//
#include <hip/hip_runtime.h>
#include <hip/hip_bf16.h>

// Problem constants: B=4,S=2048 -> T=8192 tokens, H=1024, E=8, TOP_K=2
#define H 1024
#define NEXP 8
#define T_TOK 8192
#define CAP 8192
#define TM 128
#define TN 128
#define TPB 16
#define CNTSTRIDE 32
#define NTRANS 2048   // 8 experts * 16*16 tiles of 64x64 in moe_prep

typedef __bf16 bf16x8 __attribute__((ext_vector_type(8)));
typedef __bf16 bf16x4 __attribute__((ext_vector_type(4)));
typedef float f32x4 __attribute__((ext_vector_type(4)));

__device__ __forceinline__ void async16(void* lds, const void* g) {
    __builtin_amdgcn_global_load_lds(
        (const __attribute__((address_space(1))) void*)g,
        (__attribute__((address_space(3))) void*)lds, 16, 0, 0);
}

// ---------------- prep: fused We-transpose (blocks [0,NTRANS)) + routing (rest) ----------------
// Merged to remove one launch/drain boundary and overlap the two independent streams.
__global__ __launch_bounds__(256) void moe_prep(
    const float* __restrict__ We, __bf16* __restrict__ WeT,
    const float* __restrict__ x, const float* __restrict__ Wg,
    __bf16* __restrict__ Xb, int* __restrict__ cnt,
    int* __restrict__ ltok, float* __restrict__ lgate,
    int* __restrict__ tsel, float* __restrict__ tgate) {
    __shared__ __align__(16) char smem[64 * 65 * 4];
    const int tid = threadIdx.x;

    if (blockIdx.x < NTRANS) {
        // ---- We (E,h,d) fp32 -> WeT (E,d,h) bf16, 64x64 tile ----
        float (*t)[65] = (float(*)[65])smem;   // stride 65: 2-way alias only (free, m136)
        const int tt = blockIdx.x;
        const int e  = tt >> 8;
        const int d0 = ((tt >> 4) & 15) * 64;
        const int h0 = (tt & 15) * 64;
        const int tx = tid & 15;
        const int ty = tid >> 4;
        const float* src = We + ((size_t)e << 20);
        __bf16* dst = WeT + ((size_t)e << 20);
#pragma unroll
        for (int p = 0; p < 4; ++p) {
            const int row = p * 16 + ty;
            const float4 v = *(const float4*)(src + (size_t)(h0 + row) * H + d0 + tx * 4);
            t[row][tx * 4 + 0] = v.x; t[row][tx * 4 + 1] = v.y;
            t[row][tx * 4 + 2] = v.z; t[row][tx * 4 + 3] = v.w;
        }
        __syncthreads();
#pragma unroll
        for (int p = 0; p < 4; ++p) {
            const int drow = p * 16 + ty;
            bf16x4 o;
            o[0] = (__bf16)t[tx * 4 + 0][drow];
            o[1] = (__bf16)t[tx * 4 + 1][drow];
            o[2] = (__bf16)t[tx * 4 + 2][drow];
            o[3] = (__bf16)t[tx * 4 + 3][drow];
            *(bf16x4*)(dst + (size_t)(d0 + drow) * H + h0 + tx * 4) = o;
        }
        return;
    }

    // ---- routing: fp32 logits, top-2, gates; fused x -> bf16 cast ----
    int*   sE    = (int*)smem;            // 32 ints
    float* sG    = (float*)(smem + 128);  // 32 floats
    int*   lcnt  = (int*)(smem + 256);    // 8
    int*   lbase = (int*)(smem + 288);    // 8
    int*   lslot = (int*)(smem + 320);    // 32
    const int lane = tid & 63;
    const int wave = tid >> 6;
    const int base = (blockIdx.x - NTRANS) * TPB;

    for (int i = 0; i < TPB / 4; ++i) {          // 4 tokens per wave
        const int tl = wave * (TPB / 4) + i;
        const int t  = base + tl;
        const float* xr  = x  + (size_t)t * H;
        __bf16*      xbr = Xb + (size_t)t * H;
        float a[NEXP];
#pragma unroll
        for (int e = 0; e < NEXP; ++e) a[e] = 0.f;
#pragma unroll
        for (int j = 0; j < H / 256; ++j) {
            const int h = j * 256 + lane * 4;
            const float4 xv = *(const float4*)(xr + h);
            bf16x4 xo;
            xo[0] = (__bf16)xv.x; xo[1] = (__bf16)xv.y;
            xo[2] = (__bf16)xv.z; xo[3] = (__bf16)xv.w;
            *(bf16x4*)(xbr + h) = xo;
            const float xc[4] = {xv.x, xv.y, xv.z, xv.w};
#pragma unroll
            for (int c = 0; c < 4; ++c) {
                const float4 w0 = *(const float4*)(Wg + (h + c) * NEXP);
                const float4 w1 = *(const float4*)(Wg + (h + c) * NEXP + 4);
                a[0] += xc[c] * w0.x; a[1] += xc[c] * w0.y; a[2] += xc[c] * w0.z; a[3] += xc[c] * w0.w;
                a[4] += xc[c] * w1.x; a[5] += xc[c] * w1.y; a[6] += xc[c] * w1.z; a[7] += xc[c] * w1.w;
            }
        }
#pragma unroll
        for (int e = 0; e < NEXP; ++e) {
#pragma unroll
            for (int off = 32; off > 0; off >>= 1)
                a[e] += __shfl_xor(a[e], off, 64);
        }
        int i0 = 0;
#pragma unroll
        for (int e = 1; e < NEXP; ++e) if (a[e] > a[i0]) i0 = e;   // jax tie-break: lowest idx
        int i1 = (i0 == 0) ? 1 : 0;
#pragma unroll
        for (int e = 0; e < NEXP; ++e) if (e != i0 && a[e] > a[i1]) i1 = e;
        const float ex = __expf(a[i1] - a[i0]);
        const float g0 = 1.f / (1.f + ex);
        const float g1 = ex / (1.f + ex);
        if (lane == 0) {
            sE[tl * 2] = i0; sE[tl * 2 + 1] = i1;
            sG[tl * 2] = g0; sG[tl * 2 + 1] = g1;
        }
    }
    if (tid < NEXP) lcnt[tid] = 0;
    __syncthreads();
    if (tid < TPB * 2) lslot[tid] = atomicAdd(&lcnt[sE[tid]], 1);
    __syncthreads();
    if (tid < NEXP) lbase[tid] = lcnt[tid] ? atomicAdd(&cnt[tid * CNTSTRIDE], lcnt[tid]) : 0;
    __syncthreads();
    if (tid < TPB * 2) {
        const int e = sE[tid];
        const int s = lbase[e] + lslot[tid];
        const int t = base + (tid >> 1);
        ltok[e * CAP + s]  = t;
        lgate[e * CAP + s] = sG[tid];
        tsel[t * 2 + (tid & 1)]  = e * CAP + s;
        tgate[t * 2 + (tid & 1)] = sG[tid];
    }
}

// ---------------- grouped GEMM: 128x128 tile, BK=64 (two BK=32 panels), bf16 MFMA ----------------
// R6 change: XCD-pinned swizzle. blockIdx.x = e + 8*(nt + 8*mt) -> b%8==e pins each
// expert to one XCD (round-robin dispatch model). Expert's 2MB B-panel becomes
// L2-resident; the 8 nt-blocks sharing one A-tile run on the same XCD in a tight
// dispatch window. (R6 counters: FETCH 114MB vs 34MB ideal = cross-XCD re-reads.)
__global__ __launch_bounds__(256) void moe_gemm(
    const __bf16* __restrict__ Xb, const __bf16* __restrict__ WeT,
    const float* __restrict__ be, const int* __restrict__ cnt,
    const int* __restrict__ ltok, const float* __restrict__ lgate,
    __bf16* __restrict__ Eout) {
    const int e  = blockIdx.x & 7;
    const int nt = (blockIdx.x >> 3) & 7;
    const int mt = blockIdx.x >> 6;
    const int ne = cnt[e * CNTSTRIDE];
    const int m0 = mt * TM;
    if (m0 >= ne) return;
    const int n0 = nt * TN;
    int off = 0;
    for (int i2 = 0; i2 < e; ++i2) off += cnt[i2 * CNTSTRIDE];

    __shared__ __align__(16) __bf16 smem[4 * 4096];  // Al|Al2|Bl|Bl2; epilogue: 4 x (64x64)
    __bf16* Al  = smem;
    __bf16* Al2 = smem + 4096;
    __bf16* Bl  = smem + 8192;
    __bf16* Bl2 = smem + 12288;
    __shared__ int tokL[TM];

    const int tid = threadIdx.x;
    const int lane = tid & 63;
    const int wave = tid >> 6;

    if (tid < TM) {
        const int gi = m0 + tid;
        tokL[tid] = (gi < ne) ? ltok[e * CAP + gi] : 0;
    }
    __syncthreads();

    const __bf16* Bt = WeT + ((size_t)e << 20);
    const int qr = lane >> 4;
    const int rr = lane & 15;
    const int wr = (wave >> 1) * 64;
    const int wc = (wave & 1) * 64;

    f32x4 acc[4][4];
    const f32x4 z = {0.f, 0.f, 0.f, 0.f};
#pragma unroll
    for (int i = 0; i < 4; ++i)
#pragma unroll
        for (int j = 0; j < 4; ++j) acc[i][j] = z;

    const int c0 = tid, c1 = tid + 256;
    const int ar0 = c0 >> 2, ak0 = (((c0 & 3) ^ ((c0 >> 3) & 3)) * 8);
    const int ar1 = c1 >> 2, ak1 = (((c1 & 3) ^ ((c1 >> 3) & 3)) * 8);
    const size_t arow0 = (size_t)tokL[ar0] * H;
    const size_t arow1 = (size_t)tokL[ar1] * H;
    const size_t brow0 = (size_t)(n0 + ar0) * H;
    const size_t brow1 = (size_t)(n0 + ar1) * H;

    for (int k0 = 0; k0 < H; k0 += 64) {
        async16(&Al [c0 * 8], Xb + arow0 + k0 + ak0);
        async16(&Al [c1 * 8], Xb + arow1 + k0 + ak1);
        async16(&Al2[c0 * 8], Xb + arow0 + k0 + 32 + ak0);
        async16(&Al2[c1 * 8], Xb + arow1 + k0 + 32 + ak1);
        async16(&Bl [c0 * 8], Bt + brow0 + k0 + ak0);
        async16(&Bl [c1 * 8], Bt + brow1 + k0 + ak1);
        async16(&Bl2[c0 * 8], Bt + brow0 + k0 + 32 + ak0);
        async16(&Bl2[c1 * 8], Bt + brow1 + k0 + 32 + ak1);
        __syncthreads();
        {
            bf16x8 af[4], bfr[4];
#pragma unroll
            for (int i = 0; i < 4; ++i) {
                const int ra = wr + i * 16 + rr;
                af[i] = *(const bf16x8*)&Al[ra * 32 + ((qr ^ ((ra >> 1) & 3)) * 8)];
            }
#pragma unroll
            for (int j = 0; j < 4; ++j) {
                const int rb = wc + j * 16 + rr;
                bfr[j] = *(const bf16x8*)&Bl[rb * 32 + ((qr ^ ((rb >> 1) & 3)) * 8)];
            }
#pragma unroll
            for (int i = 0; i < 4; ++i)
#pragma unroll
                for (int j = 0; j < 4; ++j)
                    acc[i][j] = __builtin_amdgcn_mfma_f32_16x16x32_bf16(af[i], bfr[j], acc[i][j], 0, 0, 0);
        }
        {
            bf16x8 af[4], bfr[4];
#pragma unroll
            for (int i = 0; i < 4; ++i) {
                const int ra = wr + i * 16 + rr;
                af[i] = *(const bf16x8*)&Al2[ra * 32 + ((qr ^ ((ra >> 1) & 3)) * 8)];
            }
#pragma unroll
            for (int j = 0; j < 4; ++j) {
                const int rb = wc + j * 16 + rr;
                bfr[j] = *(const bf16x8*)&Bl2[rb * 32 + ((qr ^ ((rb >> 1) & 3)) * 8)];
            }
#pragma unroll
            for (int i = 0; i < 4; ++i)
#pragma unroll
                for (int j = 0; j < 4; ++j)
                    acc[i][j] = __builtin_amdgcn_mfma_f32_16x16x32_bf16(af[i], bfr[j], acc[i][j], 0, 0, 0);
        }
        __syncthreads();   // also protects smem reuse by the epilogue on the last iter
    }

    float bev[4];
#pragma unroll
    for (int j = 0; j < 4; ++j) bev[j] = be[e * H + n0 + wc + j * 16 + rr];

    // ---- epilogue: per-wave 64x64 LDS stage (XOR col swizzle), then full-line bf16x8 stores ----
    __bf16* Cw = smem + wave * 4096;
#pragma unroll
    for (int i = 0; i < 4; ++i) {
#pragma unroll
        for (int reg = 0; reg < 4; ++reg) {
            const int row = i * 16 + qr * 4 + reg;      // C/D layout: col=lane&15, row=quad*4+reg
            const int key = (row & 7) * 8;
#pragma unroll
            for (int j = 0; j < 4; ++j) {
                const int c = j * 16 + rr;
                Cw[row * 64 + (c ^ key)] = (__bf16)(acc[i][j][reg] + bev[j]);
            }
        }
    }
    const int lrr = lane & 7, lrg = lane >> 3;
#pragma unroll
    for (int p = 0; p < 8; ++p) {
        const int row = p * 8 + lrg;
        const int rglob = m0 + wr + row;
        if (rglob < ne) {
            const int idx8 = ((lrr ^ (row & 7)) * 8);
            const bf16x8 v = *(const bf16x8*)&Cw[row * 64 + idx8];
            *(bf16x8*)(Eout + (size_t)(off + rglob) * H + n0 + wc + lrr * 8) = v;
        }
    }
}

// ---------------- combine: wave per token, out[t] = g0*row0 + g1*row1 ----------------
__global__ __launch_bounds__(256) void moe_combine(
    const __bf16* __restrict__ Eout, const int* __restrict__ cnt,
    const int* __restrict__ tsel, const float* __restrict__ tgate,
    float* __restrict__ out) {
    __shared__ int offs[NEXP];
    if (threadIdx.x < NEXP) {
        int o = 0;
        for (int i = 0; i < (int)threadIdx.x; ++i) o += cnt[i * CNTSTRIDE];
        offs[threadIdx.x] = o;
    }
    __syncthreads();
    const int wave = threadIdx.x >> 6, lane = threadIdx.x & 63;
    const int t = blockIdx.x * 4 + wave;
    const int sel0 = tsel[t * 2],  sel1 = tsel[t * 2 + 1];
    const float g0 = tgate[t * 2], g1  = tgate[t * 2 + 1];
    const int e0 = sel0 >> 13, s0 = sel0 & (CAP - 1);
    const int e1 = sel1 >> 13, s1 = sel1 & (CAP - 1);
    const __bf16* r0 = Eout + (size_t)(offs[e0] + s0) * H;
    const __bf16* r1 = Eout + (size_t)(offs[e1] + s1) * H;
    float* orow = out + (size_t)t * H;
#pragma unroll
    for (int c = 0; c < 4; ++c) {
        const int d = c * 256 + lane * 4;
        const bf16x4 a = *(const bf16x4*)(r0 + d);
        const bf16x4 b = *(const bf16x4*)(r1 + d);
        float4 o;
        o.x = g0 * (float)a[0] + g1 * (float)b[0];
        o.y = g0 * (float)a[1] + g1 * (float)b[1];
        o.z = g0 * (float)a[2] + g1 * (float)b[2];
        o.w = g0 * (float)a[3] + g1 * (float)b[3];
        *(float4*)(orow + d) = o;
    }
}

extern "C" void kernel_launch(void* const* d_in, const int* in_sizes, int n_in,
                              void* d_out, int out_size, void* d_ws, size_t ws_size,
                              hipStream_t stream) {
    const float* x  = (const float*)d_in[0];
    const float* Wg = (const float*)d_in[1];
    const float* We = (const float*)d_in[2];
    const float* be = (const float*)d_in[3];
    float* out = (float*)d_out;

    char* ws = (char*)d_ws;
    __bf16* Xb   = (__bf16*)ws;
    __bf16* WeT  = (__bf16*)(ws + ((size_t)16 << 20));
    __bf16* Eout = (__bf16*)(ws + ((size_t)32 << 20));
    char*   meta = ws + ((size_t)64 << 20);
    int*    cnt  = (int*)meta;
    int*    ltok = (int*)(meta + 1024);
    float*  lgat = (float*)(meta + 1024 + (size_t)NEXP * CAP * 4);
    int*    tsel = (int*)(meta + 1024 + (size_t)NEXP * CAP * 8);
    float*  tgat = (float*)(meta + 1024 + (size_t)NEXP * CAP * 8 + (size_t)T_TOK * 8);

    hipMemsetAsync(cnt, 0, NEXP * CNTSTRIDE * sizeof(int), stream);

    moe_prep<<<NTRANS + T_TOK / TPB, 256, 0, stream>>>(We, WeT, x, Wg, Xb, cnt,
                                                       ltok, lgat, tsel, tgat);
    moe_gemm<<<8 * 8 * (T_TOK / TM), 256, 0, stream>>>(Xb, WeT, be, cnt, ltok, lgat, Eout);
    moe_combine<<<T_TOK / 4, 256, 0, stream>>>(Eout, cnt, tsel, tgat, out);
}